// Round 17
// baseline (138.546 us; speedup 1.0000x reference)
//
#include <hip/hip_runtime.h>

#define TTOK 4096
#define NEXP 8
#define DDIM 512
#define FDIM 2048
#define HROWS 8576   // padded-compact row allocation (max used 8440 + slack)

typedef __attribute__((ext_vector_type(8))) short short8;
typedef __attribute__((ext_vector_type(4))) float floatx4;

#define BAR()  __builtin_amdgcn_s_barrier()
#define SBAR() __builtin_amdgcn_sched_barrier(0)

__device__ __forceinline__ ushort f2b(float f) {
  unsigned u = __float_as_uint(f);
  u += 0x7fffu + ((u >> 16) & 1u);   // round-to-nearest-even bf16
  return (ushort)(u >> 16);
}

__device__ __forceinline__ void load16(void* lds, const void* g) {
  __builtin_amdgcn_global_load_lds(
      (const __attribute__((address_space(1))) unsigned int*)g,
      (__attribute__((address_space(3))) unsigned int*)lds, 16, 0, 0);
}

// Fragment-tile layout (16x16x32 MFMA operands): matrix [R][C] stored as
// 16-row x 32-col tiles of 1KB. Tile (rt,kt) at ((rt*(C/32))+kt)*512 elems.
// elem (r,c): slot = (r&15) + 16*((c>>3)&3), ushort idx = slot*8+(c&7).
// Wave fragment read = lane l reads tile+l*16B -> conflict-free ds_read_b128.

// ---------------- fat front: logits+top2+zero-out+xb (blocks 0..1023) | w1/w3 cvt
__global__ __launch_bounds__(256) void k_front(
    const float* __restrict__ x, const float* __restrict__ gw,
    float* __restrict__ logits, int* __restrict__ tok_e,
    float2* __restrict__ tok_w, float* __restrict__ outz,
    ushort* __restrict__ xb,
    const float* __restrict__ w1, ushort* __restrict__ w1t,
    const float* __restrict__ w3, ushort* __restrict__ w3t)
{
  __shared__ ushort sm[4096];
  const int tid = threadIdx.x;
  if (blockIdx.x < TTOK / 4) {
    // zero the out rows for these 4 tokens (replaces hipMemsetAsync)
    float4 zz = {0.f, 0.f, 0.f, 0.f};
    float4* orow = (float4*)(outz + (size_t)blockIdx.x * 4 * DDIM);
    orow[tid] = zz;
    orow[tid + 256] = zz;
    const int lane = tid & 63;
    const int t = blockIdx.x * 4 + (tid >> 6);
    float xv[8];
#pragma unroll
    for (int i = 0; i < 8; ++i) xv[i] = x[(size_t)t * DDIM + lane + 64 * i];
    // bf16 copy of x (coalesced) for the gather kernel
#pragma unroll
    for (int i = 0; i < 8; ++i) xb[(size_t)t * DDIM + lane + 64 * i] = f2b(xv[i]);
    float lg[8];
#pragma unroll
    for (int e = 0; e < 8; ++e) {
      float a = 0.f;
#pragma unroll
      for (int i = 0; i < 8; ++i) a += xv[i] * gw[e * DDIM + lane + 64 * i];
#pragma unroll
      for (int s = 32; s; s >>= 1) a += __shfl_xor(a, s, 64);
      lg[e] = a;
    }
    if (lane < 8) logits[(size_t)t * 8 + lane] = lg[lane];
    if (lane == 0) {
      int i0 = 0; float v0 = lg[0];
#pragma unroll
      for (int e = 1; e < 8; ++e) { if (lg[e] > v0) { v0 = lg[e]; i0 = e; } }
      int i1 = -1; float v1 = -3.4e38f;
#pragma unroll
      for (int e = 0; e < 8; ++e) { if (e != i0 && lg[e] > v1) { v1 = lg[e]; i1 = e; } }
      float ex = expf(v1 - v0);
      float inv = 1.f / (1.f + ex);
      tok_e[t] = i0 | (i1 << 4);
      tok_w[t] = make_float2(inv, ex * inv);
    }
    return;
  }
  // w1 / w3 conversion into fragment-tiled layout (C = 512, KT = 16)
  int bid = blockIdx.x - TTOK / 4;             // 0..4095
  const float* src = (bid < 2048) ? w1 : w3;
  ushort* dst = (bid < 2048) ? w1t : w3t;
  if (bid >= 2048) bid -= 2048;
  const int r0 = (bid >> 2) * 32;
  const int c0 = (bid & 3) * 128;
#pragma unroll
  for (int i = 0; i < 4; ++i) {
    int j = i * 1024 + tid * 4;
    int lr = j >> 7, lc = j & 127;
    float4 v = *(const float4*)&src[(size_t)(r0 + lr) * 512 + c0 + lc];
    ushort4 b = { f2b(v.x), f2b(v.y), f2b(v.z), f2b(v.w) };
    int ord = (lr >> 4) * 4 + (lc >> 5);
    int slot = (lr & 15) + 16 * ((lc >> 3) & 3);
    *(ushort4*)&sm[(ord * 64 + slot) * 8 + (lc & 7)] = b;
  }
  __syncthreads();
  const size_t tb0 = ((size_t)(r0 >> 4) * 16 + (c0 >> 5)) * 512;
#pragma unroll
  for (int rt = 0; rt < 2; ++rt)
    *(short8*)&dst[tb0 + (size_t)rt * 16 * 512 + tid * 8] =
        *(const short8*)&sm[rt * 2048 + tid * 8];
}

// ---------------- router pass 2: per-expert compaction, ballot prefix
__global__ __launch_bounds__(1024) void k_build(
    const int* __restrict__ tok_e, const float2* __restrict__ tok_w,
    int* __restrict__ counts, int* __restrict__ lists, float* __restrict__ wts)
{
  const int e = blockIdx.x;
  const int tid = threadIdx.x;
  const int lane = tid & 63, wid = tid >> 6;
  __shared__ int wcnt[16];
  __shared__ int sbase;
  if (tid == 0) sbase = 0;
  __syncthreads();

  for (int c = 0; c < TTOK; c += 1024) {
    int t = c + tid;
    int pe = tok_e[t];
    bool m0 = (pe & 15) == e;
    bool m1 = ((pe >> 4) & 15) == e;
    bool m = m0 || m1;
    unsigned long long b = __ballot(m);
    int lpre = __popcll(b & ((1ull << lane) - 1ull));
    if (lane == 0) wcnt[wid] = __popcll(b);
    __syncthreads();
    int woff = 0;
#pragma unroll
    for (int i = 0; i < 16; ++i) if (i < wid) woff += wcnt[i];
    if (m) {
      float2 w = tok_w[t];
      int pos = sbase + woff + lpre;
      lists[e * TTOK + pos] = t;
      wts[e * TTOK + pos] = m0 ? w.x : w.y;
    }
    __syncthreads();
    if (tid == 0) {
      int s = 0;
#pragma unroll
      for (int i = 0; i < 16; ++i) s += wcnt[i];
      sbase += s;
    }
    __syncthreads();
  }
  if (tid == 0) counts[e] = sbase;
}

// ---------------- gather (bf16 src): x rows -> compacted fragment-tiled Xg
__global__ __launch_bounds__(256) void k_gather(
    const ushort* __restrict__ xb, const int* __restrict__ counts,
    const int* __restrict__ lists, ushort* __restrict__ Xg)
{
  int pp[9];
  pp[0] = 0;
#pragma unroll
  for (int i = 0; i < 8; ++i) pp[i + 1] = pp[i] + ((counts[i] + 31) & ~31);
  int gid = blockIdx.x * 256 + threadIdx.x;
  int gr = gid >> 6, dg = gid & 63;        // row, 8-col group
  if (gr >= pp[8]) return;
  int e = 0;
  while (e < 7 && gr >= pp[e + 1]) ++e;
  int p = gr - pp[e];
  size_t dst = ((size_t)(gr >> 4) * 16 + (dg >> 2)) * 512
             + ((gr & 15) + 16 * (dg & 3)) * 8;
  short8 o = (short8)0;
  if (p < counts[e]) {
    int t = lists[e * TTOK + p];
    o = *(const short8*)&xb[(size_t)t * DDIM + dg * 8];
  }
  *(short8*)&Xg[dst] = o;
}

// ---------------- fat GEMM1: H = silu(Xg W1^T) * (Xg W3^T)
//                  + w2 cvt, INTERLEAVED (1 cvt 8-round per 2 gemm 8-rounds)
// 8 waves (2x4), 128x128 tile, BK=32, TRIPLE-buffered (depth-2 prefetch),
// counted-vmcnt pipeline, fragment-tiled LDS (conflict-free),
// LDS-staged coalesced H epilogue
__global__ __launch_bounds__(512) void k_ffn1(
    const ushort* __restrict__ Xg, const ushort* __restrict__ w1t,
    const ushort* __restrict__ w3t, const int* __restrict__ counts,
    ushort* __restrict__ H,
    const float* __restrict__ w2, ushort* __restrict__ w2t)
{
  // 3 buffers x (X 8KB | W1 8KB | W3 8KB) = 72KB
  __shared__ ushort smem[36864];
  const int tid = threadIdx.x;

  // role by 8-block round: rounds 0,1 of each 3 -> GEMM; round 2 -> w2 cvt.
  const int grp = blockIdx.x >> 3, lane8 = blockIdx.x & 7;
  const int q3 = grp % 3, gq = grp / 3;

  if (q3 == 2) {
    // ---- w2 conversion path (C = 2048, KT = 64), 512 threads
    int bid = gq * 8 + lane8;                  // 0..2047
    ushort* sm = smem;
    const int r0 = (bid >> 4) * 32;
    const int c0 = (bid & 15) * 128;
#pragma unroll
    for (int i = 0; i < 2; ++i) {
      int j = i * 2048 + tid * 4;
      int lr = j >> 7, lc = j & 127;
      float4 v = *(const float4*)&w2[(size_t)(r0 + lr) * 2048 + c0 + lc];
      ushort4 b = { f2b(v.x), f2b(v.y), f2b(v.z), f2b(v.w) };
      int ord = (lr >> 4) * 4 + (lc >> 5);
      int slot = (lr & 15) + 16 * ((lc >> 3) & 3);
      *(ushort4*)&sm[(ord * 64 + slot) * 8 + (lc & 7)] = b;
    }
    __syncthreads();
    const size_t tb0 = ((size_t)(r0 >> 4) * 64 + (c0 >> 5)) * 512;
    int rt = tid >> 8, s = tid & 255;
    *(short8*)&w2t[tb0 + (size_t)rt * 64 * 512 + s * 8] =
        *(const short8*)&sm[rt * 2048 + s * 8];
    return;
  }

  const int gemmid = (gq * 2 + q3) * 8 + lane8;   // 0..4095, gemmid%8 == bid%8
  const int widx = (gemmid & 7) * 512 + (gemmid >> 3);
  const int mt = widx & 31, e = (widx >> 5) & 7, ft = widx >> 8;
  const int ne = counts[e];
  const int m0 = mt * 128;
  if (m0 >= ne) return;
  const int f0 = ft * 128;
  int hb = 0;
#pragma unroll
  for (int i = 0; i < 7; ++i) if (i < e) hb += (counts[i] + 31) & ~31;
  const int wid = tid >> 6, lane = tid & 63;
  const int wm = wid >> 2, wn = wid & 3;       // 2 x 4 wave grid
  const int lr = lane & 15, lgp = lane >> 4;

  const int rtX0 = (hb + m0) >> 4;
  const ushort* sx = Xg  + ((size_t)(rtX0 + wid) * 16) * 512 + lane * 8;
  const ushort* s1 = w1t + ((size_t)(e * 128 + (f0 >> 4) + wid) * 16) * 512 + lane * 8;
  const ushort* s3 = w3t + ((size_t)(e * 128 + (f0 >> 4) + wid) * 16) * 512 + lane * 8;

  // stage K-step s into buffer s%3; per-wave 1KB per tensor
#define FFN1_STAGE(B)                                                       \
  { char* base = (char*)smem + (B) * 24576 + wid * 1024;                    \
    load16(base, sx);                                                       \
    load16(base + 8192, s1);                                                \
    load16(base + 16384, s3);                                               \
    sx += 512; s1 += 512; s3 += 512; }

#define FFN1_COMPUTE(B)                                                     \
  { const ushort* cb = smem + (B) * 12288;                                  \
    short8 af[4], b1[2], b3[2];                                             \
    _Pragma("unroll")                                                       \
    for (int mf = 0; mf < 4; ++mf)                                          \
      af[mf] = *(const short8*)&cb[(wm * 4 + mf) * 512 + lane * 8];         \
    _Pragma("unroll")                                                       \
    for (int nf = 0; nf < 2; ++nf) {                                        \
      b1[nf] = *(const short8*)&cb[4096 + (wn * 2 + nf) * 512 + lane * 8];  \
      b3[nf] = *(const short8*)&cb[8192 + (wn * 2 + nf) * 512 + lane * 8];  \
    }                                                                       \
    _Pragma("unroll")                                                       \
    for (int mf = 0; mf < 4; ++mf)                                          \
      _Pragma("unroll")                                                     \
      for (int nf = 0; nf < 2; ++nf) {                                      \
        acc1[mf][nf] = __builtin_amdgcn_mfma_f32_16x16x32_bf16(             \
            af[mf], b1[nf], acc1[mf][nf], 0, 0, 0);                         \
        acc3[mf][nf] = __builtin_amdgcn_mfma_f32_16x16x32_bf16(             \
            af[mf], b3[nf], acc3[mf][nf], 0, 0, 0);                         \
      } }

  floatx4 acc1[4][2], acc3[4][2];
#pragma unroll
  for (int a = 0; a < 4; ++a)
#pragma unroll
    for (int b = 0; b < 2; ++b) { acc1[a][b] = (floatx4)0.f; acc3[a][b] = (floatx4)0.f; }

  // depth-2 counted-vmcnt pipeline. 3 loads/stage/wave; at the wait point
  // stages {t, t+1, t+2} are outstanding (9 loads) -> vmcnt(6) drains stage t.
  FFN1_STAGE(0);
  FFN1_STAGE(1);
#pragma unroll
  for (int t = 0; t < 16; ++t) {                       // K = 512/32
    if (t + 2 < 16) FFN1_STAGE((t + 2) % 3);
    if (t < 14)      asm volatile("s_waitcnt vmcnt(6)" ::: "memory");
    else if (t < 15) asm volatile("s_waitcnt vmcnt(3)" ::: "memory");
    else             asm volatile("s_waitcnt vmcnt(0)" ::: "memory");
    BAR(); SBAR();
    FFN1_COMPUTE(t % 3);
    SBAR(); BAR();
  }

  // epilogue: silu*mul -> stage H tile (128x128) in LDS fragment-tile layout,
  // then coalesced short8 stores (row-guarded).
  __syncthreads();                    // all waves done with staging buffers
  ushort* hstage = smem;              // reuse 32KB of the 72KB staging LDS
#pragma unroll
  for (int mf = 0; mf < 4; ++mf) {
#pragma unroll
    for (int nf = 0; nf < 2; ++nf) {
      const int tloc = (wm * 4 + mf) * 4 + wn;        // local tile 0..31
      const int slotc = (nf * 2 + (lr >> 3)) & 3;
      const int bidx = tloc * 512 + slotc * 128 + (lr & 7);
      floatx4 v1 = acc1[mf][nf], v3 = acc3[mf][nf];
#pragma unroll
      for (int j = 0; j < 4; ++j) {
        float h1 = v1[j], h3 = v3[j];
        float sig = 1.f / (1.f + __expf(-h1));
        hstage[bidx + (lgp * 4 + j) * 8] = f2b(h1 * sig * h3);
      }
    }
  }
  __syncthreads();
  const int ktBase = f0 >> 5;
#pragma unroll
  for (int i = 0; i < 4; ++i) {
    int s = i * 512 + tid;            // short8 index 0..2047
    int tloc = s >> 6, off = s & 63;  // tile, slot
    int rt_l = tloc >> 2, kt_l = tloc & 3;
    if (m0 + rt_l * 16 + (off & 15) < ne)
      *(short8*)&H[((size_t)(rtX0 + rt_l) * 64 + ktBase + kt_l) * 512 + off * 8] =
          *(const short8*)&hstage[s * 8];
  }
#undef FFN1_STAGE
#undef FFN1_COMPUTE
}

// ---------------- GEMM2: Y = H W2^T, BK=64, K-split 2, R9 counted-vmcnt
__global__ __launch_bounds__(512) void k_ffn2(
    const ushort* __restrict__ Ht, const ushort* __restrict__ w2t,
    const int* __restrict__ counts, const int* __restrict__ lists,
    const float* __restrict__ wts, float* __restrict__ out)
{
  const int bid = blockIdx.x;                  // nwg = 2048
  const int widx = (bid & 7) * 256 + (bid >> 3);
  const int mt = widx & 31, e = (widx >> 5) & 7;
  const int rest = widx >> 8;                  // 0..7
  const int dt = rest & 3, ks = rest >> 2;
  const int ne = counts[e];
  const int m0 = mt * 128;
  if (m0 >= ne) return;
  const int d0 = dt * 128;
  int hb = 0;
#pragma unroll
  for (int i = 0; i < 7; ++i) if (i < e) hb += (counts[i] + 31) & ~31;
  const int tid = threadIdx.x;
  const int wid = tid >> 6, lane = tid & 63;
  const int wm = wid >> 2, wn = wid & 3;
  const int lr = lane & 15, lgp = lane >> 4;

  __shared__ ushort Hls[2][8192], W2ls[2][8192];
  __shared__ int toks[128];
  __shared__ float twt[128];

  if (tid < 128) {
    int p = m0 + tid;
    bool v = p < ne;
    toks[tid] = v ? lists[e * TTOK + p] : 0;
    twt[tid] = v ? wts[e * TTOK + p] : 0.f;
  }

  const int rtH0 = (hb + m0) >> 4;
  const int kb = ks * 32;                      // K-tile base (32-col units)
  const ushort* sh = Ht  + ((size_t)(rtH0 + wid) * 64 + kb) * 512 + lane * 8;
  const ushort* sw = w2t + ((size_t)(e * 32 + (d0 >> 4) + wid) * 64 + kb) * 512 + lane * 8;

#define FFN2_STAGE(B)                                                      \
  { load16((char*)&Hls[B][0]  + (wid * 2) * 1024, sh);                     \
    load16((char*)&Hls[B][0]  + (wid * 2 + 1) * 1024, sh + 512);           \
    load16((char*)&W2ls[B][0] + (wid * 2) * 1024, sw);                     \
    load16((char*)&W2ls[B][0] + (wid * 2 + 1) * 1024, sw + 512);           \
    sh += 1024; sw += 1024; }

#define FFN2_COMPUTE(B)                                                    \
  { _Pragma("unroll")                                                      \
    for (int kk = 0; kk < 2; ++kk) {                                       \
      short8 af[4], bf[2];                                                 \
      _Pragma("unroll")                                                    \
      for (int mf = 0; mf < 4; ++mf)                                       \
        af[mf] = *(const short8*)&Hls[B][((wm * 4 + mf) * 2 + kk) * 512 + lane * 8]; \
      _Pragma("unroll")                                                    \
      for (int nf = 0; nf < 2; ++nf)                                       \
        bf[nf] = *(const short8*)&W2ls[B][((wn * 2 + nf) * 2 + kk) * 512 + lane * 8]; \
      _Pragma("unroll")                                                    \
      for (int mf = 0; mf < 4; ++mf)                                       \
        _Pragma("unroll")                                                  \
        for (int nf = 0; nf < 2; ++nf)                                     \
          acc[mf][nf] = __builtin_amdgcn_mfma_f32_16x16x32_bf16(           \
              af[mf], bf[nf], acc[mf][nf], 0, 0, 0);                       \
    } }

  floatx4 acc[4][2];
#pragma unroll
  for (int a = 0; a < 4; ++a)
#pragma unroll
    for (int b = 0; b < 2; ++b) acc[a][b] = (floatx4)0.f;

  FFN2_STAGE(0);
  for (int t = 0; t < 16; t += 2) {            // K = 1024/64 per split
    FFN2_STAGE(1);
    asm volatile("s_waitcnt vmcnt(4)" ::: "memory");
    BAR(); SBAR();
    FFN2_COMPUTE(0);
    SBAR(); BAR();
    if (t + 2 < 16) {
      FFN2_STAGE(0);
      asm volatile("s_waitcnt vmcnt(4)" ::: "memory");
    } else {
      asm volatile("s_waitcnt vmcnt(0)" ::: "memory");
    }
    BAR(); SBAR();
    FFN2_COMPUTE(1);
    SBAR(); BAR();
  }

#pragma unroll
  for (int mf = 0; mf < 4; ++mf) {
#pragma unroll
    for (int j = 0; j < 4; ++j) {
      int rloc = wm * 64 + mf * 16 + lgp * 4 + j;
      int p = m0 + rloc;
      if (p < ne) {
        int t = toks[rloc];
        float w = twt[rloc];
#pragma unroll
        for (int nf = 0; nf < 2; ++nf) {
          int d = d0 + wn * 32 + nf * 16 + lr;
          atomicAdd(&out[(size_t)t * DDIM + d], w * acc[mf][nf][j]);
        }
      }
    }
  }
#undef FFN2_STAGE
#undef FFN2_COMPUTE
}

extern "C" void kernel_launch(void* const* d_in, const int* in_sizes, int n_in,
                              void* d_out, int out_size, void* d_ws, size_t ws_size,
                              hipStream_t stream) {
  const float* x  = (const float*)d_in[0];
  const float* gw = (const float*)d_in[1];
  const float* w1 = (const float*)d_in[2];
  const float* w2 = (const float*)d_in[3];
  const float* w3 = (const float*)d_in[4];
  float* out = (float*)d_out;
  float* logits = out + (size_t)TTOK * DDIM;

  // workspace layout (~99 MB)
  int* counts = (int*)d_ws;                        // [8] (pad to 16)
  int* tok_e  = counts + 16;                       // [4096]
  float2* tok_w = (float2*)(tok_e + TTOK);         // [4096]
  int* lists  = (int*)(tok_w + TTOK);              // [8][4096]
  float* wts  = (float*)(lists + NEXP * TTOK);     // [8][4096]
  ushort* xb  = (ushort*)(wts + NEXP * TTOK);      // [4096][512] bf16 rows
  ushort* w1t = xb + (size_t)TTOK * DDIM;          // tiled
  ushort* w3t = w1t + (size_t)NEXP * FDIM * DDIM;
  ushort* w2t = w3t + (size_t)NEXP * FDIM * DDIM;  // tiled
  ushort* Xg  = w2t + (size_t)NEXP * DDIM * FDIM;  // tiled [HROWS][512]
  ushort* H   = Xg + (size_t)HROWS * DDIM;         // tiled [HROWS][2048]

  k_front<<<TTOK / 4 + 4096, 256, 0, stream>>>(x, gw, logits, tok_e, tok_w,
                                               out, xb, w1, w1t, w3, w3t);
  k_build<<<NEXP, 1024, 0, stream>>>(tok_e, tok_w, counts, lists, wts);
  k_gather<<<(8448 * 64) / 256, 256, 0, stream>>>(xb, counts, lists, Xg);

  k_ffn1<<<4096 + 2048, 512, 0, stream>>>(Xg, w1t, w3t, counts, H, w2, w2t);
  k_ffn2<<<2048, 512, 0, stream>>>(H, w2t, counts, lists, wts, out);
}

// Round 18
// 136.830 us; speedup vs baseline: 1.0125x; 1.0125x over previous
//
#include <hip/hip_runtime.h>

#define TTOK 4096
#define NEXP 8
#define DDIM 512
#define FDIM 2048
#define HROWS 8576   // padded-compact row allocation (max used 8440 + slack)

typedef __attribute__((ext_vector_type(8))) short short8;
typedef __attribute__((ext_vector_type(4))) float floatx4;

#define BAR()  __builtin_amdgcn_s_barrier()
#define SBAR() __builtin_amdgcn_sched_barrier(0)

__device__ __forceinline__ ushort f2b(float f) {
  unsigned u = __float_as_uint(f);
  u += 0x7fffu + ((u >> 16) & 1u);   // round-to-nearest-even bf16
  return (ushort)(u >> 16);
}

__device__ __forceinline__ void load16(void* lds, const void* g) {
  __builtin_amdgcn_global_load_lds(
      (const __attribute__((address_space(1))) unsigned int*)g,
      (__attribute__((address_space(3))) unsigned int*)lds, 16, 0, 0);
}

// Fragment-tile layout (16x16x32 MFMA operands): matrix [R][C] stored as
// 16-row x 32-col tiles of 1KB. Tile (rt,kt) at ((rt*(C/32))+kt)*512 elems.
// elem (r,c): slot = (r&15) + 16*((c>>3)&3), ushort idx = slot*8+(c&7).
// Wave fragment read = lane l reads tile+l*16B -> conflict-free ds_read_b128.

// ---------------- fat front: logits+top2+zero-out+xb (blocks 0..1023) | w1/w3 cvt
__global__ __launch_bounds__(256) void k_front(
    const float* __restrict__ x, const float* __restrict__ gw,
    float* __restrict__ logits, int* __restrict__ tok_e,
    float2* __restrict__ tok_w, float* __restrict__ outz,
    ushort* __restrict__ xb,
    const float* __restrict__ w1, ushort* __restrict__ w1t,
    const float* __restrict__ w3, ushort* __restrict__ w3t)
{
  __shared__ ushort sm[4096];
  const int tid = threadIdx.x;
  if (blockIdx.x < TTOK / 4) {
    // zero the out rows for these 4 tokens (replaces hipMemsetAsync)
    float4 zz = {0.f, 0.f, 0.f, 0.f};
    float4* orow = (float4*)(outz + (size_t)blockIdx.x * 4 * DDIM);
    orow[tid] = zz;
    orow[tid + 256] = zz;
    const int lane = tid & 63;
    const int t = blockIdx.x * 4 + (tid >> 6);
    float xv[8];
#pragma unroll
    for (int i = 0; i < 8; ++i) xv[i] = x[(size_t)t * DDIM + lane + 64 * i];
    // bf16 copy of x (coalesced) for ffn1's gathered staging
#pragma unroll
    for (int i = 0; i < 8; ++i) xb[(size_t)t * DDIM + lane + 64 * i] = f2b(xv[i]);
    float lg[8];
#pragma unroll
    for (int e = 0; e < 8; ++e) {
      float a = 0.f;
#pragma unroll
      for (int i = 0; i < 8; ++i) a += xv[i] * gw[e * DDIM + lane + 64 * i];
#pragma unroll
      for (int s = 32; s; s >>= 1) a += __shfl_xor(a, s, 64);
      lg[e] = a;
    }
    if (lane < 8) logits[(size_t)t * 8 + lane] = lg[lane];
    if (lane == 0) {
      int i0 = 0; float v0 = lg[0];
#pragma unroll
      for (int e = 1; e < 8; ++e) { if (lg[e] > v0) { v0 = lg[e]; i0 = e; } }
      int i1 = -1; float v1 = -3.4e38f;
#pragma unroll
      for (int e = 0; e < 8; ++e) { if (e != i0 && lg[e] > v1) { v1 = lg[e]; i1 = e; } }
      float ex = expf(v1 - v0);
      float inv = 1.f / (1.f + ex);
      tok_e[t] = i0 | (i1 << 4);
      tok_w[t] = make_float2(inv, ex * inv);
    }
    return;
  }
  // w1 / w3 conversion into fragment-tiled layout (C = 512, KT = 16)
  int bid = blockIdx.x - TTOK / 4;             // 0..4095
  const float* src = (bid < 2048) ? w1 : w3;
  ushort* dst = (bid < 2048) ? w1t : w3t;
  if (bid >= 2048) bid -= 2048;
  const int r0 = (bid >> 2) * 32;
  const int c0 = (bid & 3) * 128;
#pragma unroll
  for (int i = 0; i < 4; ++i) {
    int j = i * 1024 + tid * 4;
    int lr = j >> 7, lc = j & 127;
    float4 v = *(const float4*)&src[(size_t)(r0 + lr) * 512 + c0 + lc];
    ushort4 b = { f2b(v.x), f2b(v.y), f2b(v.z), f2b(v.w) };
    int ord = (lr >> 4) * 4 + (lc >> 5);
    int slot = (lr & 15) + 16 * ((lc >> 3) & 3);
    *(ushort4*)&sm[(ord * 64 + slot) * 8 + (lc & 7)] = b;
  }
  __syncthreads();
  const size_t tb0 = ((size_t)(r0 >> 4) * 16 + (c0 >> 5)) * 512;
#pragma unroll
  for (int rt = 0; rt < 2; ++rt)
    *(short8*)&dst[tb0 + (size_t)rt * 16 * 512 + tid * 8] =
        *(const short8*)&sm[rt * 2048 + tid * 8];
}

// ---------------- router pass 2: per-expert compaction, ballot prefix
__global__ __launch_bounds__(1024) void k_build(
    const int* __restrict__ tok_e, const float2* __restrict__ tok_w,
    int* __restrict__ counts, int* __restrict__ lists, float* __restrict__ wts)
{
  const int e = blockIdx.x;
  const int tid = threadIdx.x;
  const int lane = tid & 63, wid = tid >> 6;
  __shared__ int wcnt[16];
  __shared__ int sbase;
  if (tid == 0) sbase = 0;
  __syncthreads();

  for (int c = 0; c < TTOK; c += 1024) {
    int t = c + tid;
    int pe = tok_e[t];
    bool m0 = (pe & 15) == e;
    bool m1 = ((pe >> 4) & 15) == e;
    bool m = m0 || m1;
    unsigned long long b = __ballot(m);
    int lpre = __popcll(b & ((1ull << lane) - 1ull));
    if (lane == 0) wcnt[wid] = __popcll(b);
    __syncthreads();
    int woff = 0;
#pragma unroll
    for (int i = 0; i < 16; ++i) if (i < wid) woff += wcnt[i];
    if (m) {
      float2 w = tok_w[t];
      int pos = sbase + woff + lpre;
      lists[e * TTOK + pos] = t;
      wts[e * TTOK + pos] = m0 ? w.x : w.y;
    }
    __syncthreads();
    if (tid == 0) {
      int s = 0;
#pragma unroll
      for (int i = 0; i < 16; ++i) s += wcnt[i];
      sbase += s;
    }
    __syncthreads();
  }
  if (tid == 0) counts[e] = sbase;
}

// ---------------- fat GEMM1: H = silu(X W1^T) * (X W3^T)
//                  + w2 cvt, INTERLEAVED (1 cvt 8-round per 2 gemm 8-rounds)
// 8 waves (2x4), 128x128 tile, BK=32, TRIPLE-buffered (depth-2 prefetch),
// counted-vmcnt pipeline, fragment-tiled LDS (conflict-free),
// X staged by DIRECT per-lane gather from xb (no Xg intermediate),
// LDS-staged coalesced H epilogue
__global__ __launch_bounds__(512) void k_ffn1(
    const ushort* __restrict__ xb, const ushort* __restrict__ w1t,
    const ushort* __restrict__ w3t, const int* __restrict__ counts,
    const int* __restrict__ lists, ushort* __restrict__ H,
    const float* __restrict__ w2, ushort* __restrict__ w2t)
{
  // 3 buffers x (X 8KB | W1 8KB | W3 8KB) = 72KB
  __shared__ ushort smem[36864];
  __shared__ int toksL[128];
  const int tid = threadIdx.x;

  // role by 8-block round: rounds 0,1 of each 3 -> GEMM; round 2 -> w2 cvt.
  const int grp = blockIdx.x >> 3, lane8 = blockIdx.x & 7;
  const int q3 = grp % 3, gq = grp / 3;

  if (q3 == 2) {
    // ---- w2 conversion path (C = 2048, KT = 64), 512 threads
    int bid = gq * 8 + lane8;                  // 0..2047
    ushort* sm = smem;
    const int r0 = (bid >> 4) * 32;
    const int c0 = (bid & 15) * 128;
#pragma unroll
    for (int i = 0; i < 2; ++i) {
      int j = i * 2048 + tid * 4;
      int lr = j >> 7, lc = j & 127;
      float4 v = *(const float4*)&w2[(size_t)(r0 + lr) * 2048 + c0 + lc];
      ushort4 b = { f2b(v.x), f2b(v.y), f2b(v.z), f2b(v.w) };
      int ord = (lr >> 4) * 4 + (lc >> 5);
      int slot = (lr & 15) + 16 * ((lc >> 3) & 3);
      *(ushort4*)&sm[(ord * 64 + slot) * 8 + (lc & 7)] = b;
    }
    __syncthreads();
    const size_t tb0 = ((size_t)(r0 >> 4) * 64 + (c0 >> 5)) * 512;
    int rt = tid >> 8, s = tid & 255;
    *(short8*)&w2t[tb0 + (size_t)rt * 64 * 512 + s * 8] =
        *(const short8*)&sm[rt * 2048 + s * 8];
    return;
  }

  const int gemmid = (gq * 2 + q3) * 8 + lane8;   // 0..4095, gemmid%8 == bid%8
  const int widx = (gemmid & 7) * 512 + (gemmid >> 3);
  const int mt = widx & 31, e = (widx >> 5) & 7, ft = widx >> 8;
  const int ne = counts[e];
  const int m0 = mt * 128;
  if (m0 >= ne) return;
  const int f0 = ft * 128;
  int hb = 0;
#pragma unroll
  for (int i = 0; i < 7; ++i) if (i < e) hb += (counts[i] + 31) & ~31;
  const int wid = tid >> 6, lane = tid & 63;
  const int wm = wid >> 2, wn = wid & 3;       // 2 x 4 wave grid
  const int lr = lane & 15, lgp = lane >> 4;

  // token list for this block's 128 rows (clamped; out-of-range rows are
  // discarded by the epilogue store guard)
  if (tid < 128) {
    int p = m0 + tid;
    toksL[tid] = (p < ne) ? lists[e * TTOK + p] : lists[e * TTOK];
  }
  __syncthreads();

  const int rtX0 = (hb + m0) >> 4;
  // X staging: lane l stages row toksL[wid*16+(l&15)], colgroup (l>>4)
  const ushort* sx = xb + (size_t)toksL[wid * 16 + lr] * DDIM + lgp * 8;
  const ushort* s1 = w1t + ((size_t)(e * 128 + (f0 >> 4) + wid) * 16) * 512 + lane * 8;
  const ushort* s3 = w3t + ((size_t)(e * 128 + (f0 >> 4) + wid) * 16) * 512 + lane * 8;

  // stage K-step s into buffer s%3; per-wave 1KB per tensor
#define FFN1_STAGE(B)                                                       \
  { char* base = (char*)smem + (B) * 24576 + wid * 1024;                    \
    load16(base, sx);                                                       \
    load16(base + 8192, s1);                                                \
    load16(base + 16384, s3);                                               \
    sx += 32; s1 += 512; s3 += 512; }

#define FFN1_COMPUTE(B)                                                     \
  { const ushort* cb = smem + (B) * 12288;                                  \
    short8 af[4], b1[2], b3[2];                                             \
    _Pragma("unroll")                                                       \
    for (int mf = 0; mf < 4; ++mf)                                          \
      af[mf] = *(const short8*)&cb[(wm * 4 + mf) * 512 + lane * 8];         \
    _Pragma("unroll")                                                       \
    for (int nf = 0; nf < 2; ++nf) {                                        \
      b1[nf] = *(const short8*)&cb[4096 + (wn * 2 + nf) * 512 + lane * 8];  \
      b3[nf] = *(const short8*)&cb[8192 + (wn * 2 + nf) * 512 + lane * 8];  \
    }                                                                       \
    _Pragma("unroll")                                                       \
    for (int mf = 0; mf < 4; ++mf)                                          \
      _Pragma("unroll")                                                     \
      for (int nf = 0; nf < 2; ++nf) {                                      \
        acc1[mf][nf] = __builtin_amdgcn_mfma_f32_16x16x32_bf16(             \
            af[mf], b1[nf], acc1[mf][nf], 0, 0, 0);                         \
        acc3[mf][nf] = __builtin_amdgcn_mfma_f32_16x16x32_bf16(             \
            af[mf], b3[nf], acc3[mf][nf], 0, 0, 0);                         \
      } }

  floatx4 acc1[4][2], acc3[4][2];
#pragma unroll
  for (int a = 0; a < 4; ++a)
#pragma unroll
    for (int b = 0; b < 2; ++b) { acc1[a][b] = (floatx4)0.f; acc3[a][b] = (floatx4)0.f; }

  // depth-2 counted-vmcnt pipeline. 3 loads/stage/wave; at the wait point
  // stages {t, t+1, t+2} are outstanding (9 loads) -> vmcnt(6) drains stage t.
  FFN1_STAGE(0);
  FFN1_STAGE(1);
#pragma unroll
  for (int t = 0; t < 16; ++t) {                       // K = 512/32
    if (t + 2 < 16) FFN1_STAGE((t + 2) % 3);
    if (t < 14)      asm volatile("s_waitcnt vmcnt(6)" ::: "memory");
    else if (t < 15) asm volatile("s_waitcnt vmcnt(3)" ::: "memory");
    else             asm volatile("s_waitcnt vmcnt(0)" ::: "memory");
    BAR(); SBAR();
    FFN1_COMPUTE(t % 3);
    SBAR(); BAR();
  }

  // epilogue: silu*mul -> stage H tile (128x128) in LDS fragment-tile layout,
  // then coalesced short8 stores (row-guarded).
  __syncthreads();                    // all waves done with staging buffers
  ushort* hstage = smem;              // reuse 32KB of the 72KB staging LDS
#pragma unroll
  for (int mf = 0; mf < 4; ++mf) {
#pragma unroll
    for (int nf = 0; nf < 2; ++nf) {
      const int tloc = (wm * 4 + mf) * 4 + wn;        // local tile 0..31
      const int slotc = (nf * 2 + (lr >> 3)) & 3;
      const int bidx = tloc * 512 + slotc * 128 + (lr & 7);
      floatx4 v1 = acc1[mf][nf], v3 = acc3[mf][nf];
#pragma unroll
      for (int j = 0; j < 4; ++j) {
        float h1 = v1[j], h3 = v3[j];
        float sig = 1.f / (1.f + __expf(-h1));
        hstage[bidx + (lgp * 4 + j) * 8] = f2b(h1 * sig * h3);
      }
    }
  }
  __syncthreads();
  const int ktBase = f0 >> 5;
#pragma unroll
  for (int i = 0; i < 4; ++i) {
    int s = i * 512 + tid;            // short8 index 0..2047
    int tloc = s >> 6, off = s & 63;  // tile, slot
    int rt_l = tloc >> 2, kt_l = tloc & 3;
    if (m0 + rt_l * 16 + (off & 15) < ne)
      *(short8*)&H[((size_t)(rtX0 + rt_l) * 64 + ktBase + kt_l) * 512 + off * 8] =
          *(const short8*)&hstage[s * 8];
  }
#undef FFN1_STAGE
#undef FFN1_COMPUTE
}

// ---------------- GEMM2: Y = H W2^T, BK=64, K-split 2, R9 counted-vmcnt
__global__ __launch_bounds__(512) void k_ffn2(
    const ushort* __restrict__ Ht, const ushort* __restrict__ w2t,
    const int* __restrict__ counts, const int* __restrict__ lists,
    const float* __restrict__ wts, float* __restrict__ out)
{
  const int bid = blockIdx.x;                  // nwg = 2048
  const int widx = (bid & 7) * 256 + (bid >> 3);
  const int mt = widx & 31, e = (widx >> 5) & 7;
  const int rest = widx >> 8;                  // 0..7
  const int dt = rest & 3, ks = rest >> 2;
  const int ne = counts[e];
  const int m0 = mt * 128;
  if (m0 >= ne) return;
  const int d0 = dt * 128;
  int hb = 0;
#pragma unroll
  for (int i = 0; i < 7; ++i) if (i < e) hb += (counts[i] + 31) & ~31;
  const int tid = threadIdx.x;
  const int wid = tid >> 6, lane = tid & 63;
  const int wm = wid >> 2, wn = wid & 3;
  const int lr = lane & 15, lgp = lane >> 4;

  __shared__ ushort Hls[2][8192], W2ls[2][8192];
  __shared__ int toks[128];
  __shared__ float twt[128];

  if (tid < 128) {
    int p = m0 + tid;
    bool v = p < ne;
    toks[tid] = v ? lists[e * TTOK + p] : 0;
    twt[tid] = v ? wts[e * TTOK + p] : 0.f;
  }

  const int rtH0 = (hb + m0) >> 4;
  const int kb = ks * 32;                      // K-tile base (32-col units)
  const ushort* sh = Ht  + ((size_t)(rtH0 + wid) * 64 + kb) * 512 + lane * 8;
  const ushort* sw = w2t + ((size_t)(e * 32 + (d0 >> 4) + wid) * 64 + kb) * 512 + lane * 8;

#define FFN2_STAGE(B)                                                      \
  { load16((char*)&Hls[B][0]  + (wid * 2) * 1024, sh);                     \
    load16((char*)&Hls[B][0]  + (wid * 2 + 1) * 1024, sh + 512);           \
    load16((char*)&W2ls[B][0] + (wid * 2) * 1024, sw);                     \
    load16((char*)&W2ls[B][0] + (wid * 2 + 1) * 1024, sw + 512);           \
    sh += 1024; sw += 1024; }

#define FFN2_COMPUTE(B)                                                    \
  { _Pragma("unroll")                                                      \
    for (int kk = 0; kk < 2; ++kk) {                                       \
      short8 af[4], bf[2];                                                 \
      _Pragma("unroll")                                                    \
      for (int mf = 0; mf < 4; ++mf)                                       \
        af[mf] = *(const short8*)&Hls[B][((wm * 4 + mf) * 2 + kk) * 512 + lane * 8]; \
      _Pragma("unroll")                                                    \
      for (int nf = 0; nf < 2; ++nf)                                       \
        bf[nf] = *(const short8*)&W2ls[B][((wn * 2 + nf) * 2 + kk) * 512 + lane * 8]; \
      _Pragma("unroll")                                                    \
      for (int mf = 0; mf < 4; ++mf)                                       \
        _Pragma("unroll")                                                  \
        for (int nf = 0; nf < 2; ++nf)                                     \
          acc[mf][nf] = __builtin_amdgcn_mfma_f32_16x16x32_bf16(           \
              af[mf], bf[nf], acc[mf][nf], 0, 0, 0);                       \
    } }

  floatx4 acc[4][2];
#pragma unroll
  for (int a = 0; a < 4; ++a)
#pragma unroll
    for (int b = 0; b < 2; ++b) acc[a][b] = (floatx4)0.f;

  FFN2_STAGE(0);
  for (int t = 0; t < 16; t += 2) {            // K = 1024/64 per split
    FFN2_STAGE(1);
    asm volatile("s_waitcnt vmcnt(4)" ::: "memory");
    BAR(); SBAR();
    FFN2_COMPUTE(0);
    SBAR(); BAR();
    if (t + 2 < 16) {
      FFN2_STAGE(0);
      asm volatile("s_waitcnt vmcnt(4)" ::: "memory");
    } else {
      asm volatile("s_waitcnt vmcnt(0)" ::: "memory");
    }
    BAR(); SBAR();
    FFN2_COMPUTE(1);
    SBAR(); BAR();
  }

#pragma unroll
  for (int mf = 0; mf < 4; ++mf) {
#pragma unroll
    for (int j = 0; j < 4; ++j) {
      int rloc = wm * 64 + mf * 16 + lgp * 4 + j;
      int p = m0 + rloc;
      if (p < ne) {
        int t = toks[rloc];
        float w = twt[rloc];
#pragma unroll
        for (int nf = 0; nf < 2; ++nf) {
          int d = d0 + wn * 32 + nf * 16 + lr;
          atomicAdd(&out[(size_t)t * DDIM + d], w * acc[mf][nf][j]);
        }
      }
    }
  }
#undef FFN2_STAGE
#undef FFN2_COMPUTE
}

extern "C" void kernel_launch(void* const* d_in, const int* in_sizes, int n_in,
                              void* d_out, int out_size, void* d_ws, size_t ws_size,
                              hipStream_t stream) {
  const float* x  = (const float*)d_in[0];
  const float* gw = (const float*)d_in[1];
  const float* w1 = (const float*)d_in[2];
  const float* w2 = (const float*)d_in[3];
  const float* w3 = (const float*)d_in[4];
  float* out = (float*)d_out;
  float* logits = out + (size_t)TTOK * DDIM;

  // workspace layout (~90 MB)
  int* counts = (int*)d_ws;                        // [8] (pad to 16)
  int* tok_e  = counts + 16;                       // [4096]
  float2* tok_w = (float2*)(tok_e + TTOK);         // [4096]
  int* lists  = (int*)(tok_w + TTOK);              // [8][4096]
  float* wts  = (float*)(lists + NEXP * TTOK);     // [8][4096]
  ushort* xb  = (ushort*)(wts + NEXP * TTOK);      // [4096][512] bf16 rows
  ushort* w1t = xb + (size_t)TTOK * DDIM;          // tiled
  ushort* w3t = w1t + (size_t)NEXP * FDIM * DDIM;
  ushort* w2t = w3t + (size_t)NEXP * FDIM * DDIM;  // tiled
  ushort* H   = w2t + (size_t)NEXP * DDIM * FDIM;  // tiled [HROWS][2048]

  k_front<<<TTOK / 4 + 4096, 256, 0, stream>>>(x, gw, logits, tok_e, tok_w,
                                               out, xb, w1, w1t, w3, w3t);
  k_build<<<NEXP, 1024, 0, stream>>>(tok_e, tok_w, counts, lists, wts);

  k_ffn1<<<4096 + 2048, 512, 0, stream>>>(xb, w1t, w3t, counts, lists, H, w2, w2t);
  k_ffn2<<<2048, 512, 0, stream>>>(H, w2t, counts, lists, wts, out);
}

// Round 20
// 134.017 us; speedup vs baseline: 1.0338x; 1.0210x over previous
//
#include <hip/hip_runtime.h>

#define TTOK 4096
#define NEXP 8
#define DDIM 512
#define FDIM 2048
#define HROWS 8576   // padded-compact row allocation (max used 8440 + slack)

typedef __attribute__((ext_vector_type(8))) short short8;
typedef __attribute__((ext_vector_type(4))) float floatx4;

#define BAR()  __builtin_amdgcn_s_barrier()
#define SBAR() __builtin_amdgcn_sched_barrier(0)

__device__ __forceinline__ ushort f2b(float f) {
  unsigned u = __float_as_uint(f);
  u += 0x7fffu + ((u >> 16) & 1u);   // round-to-nearest-even bf16
  return (ushort)(u >> 16);
}

__device__ __forceinline__ void load16(void* lds, const void* g) {
  __builtin_amdgcn_global_load_lds(
      (const __attribute__((address_space(1))) unsigned int*)g,
      (__attribute__((address_space(3))) unsigned int*)lds, 16, 0, 0);
}

// Fragment-tile layout (16x16x32 MFMA operands): matrix [R][C] stored as
// 16-row x 32-col tiles of 1KB. Tile (rt,kt) at ((rt*(C/32))+kt)*512 elems.
// elem (r,c): slot = (r&15) + 16*((c>>3)&3), ushort idx = slot*8+(c&7).
// Wave fragment read = lane l reads tile+l*16B -> conflict-free ds_read_b128.

// ---------------- fat front: logits+top2+zero-out+xb (blocks 0..1023) | w1/w3 cvt
__global__ __launch_bounds__(256) void k_front(
    const float* __restrict__ x, const float* __restrict__ gw,
    float* __restrict__ logits, int* __restrict__ tok_e,
    float2* __restrict__ tok_w, float* __restrict__ outz,
    ushort* __restrict__ xb,
    const float* __restrict__ w1, ushort* __restrict__ w1t,
    const float* __restrict__ w3, ushort* __restrict__ w3t)
{
  __shared__ ushort sm[4096];
  const int tid = threadIdx.x;
  if (blockIdx.x < TTOK / 4) {
    // zero the out rows for these 4 tokens (replaces hipMemsetAsync)
    float4 zz = {0.f, 0.f, 0.f, 0.f};
    float4* orow = (float4*)(outz + (size_t)blockIdx.x * 4 * DDIM);
    orow[tid] = zz;
    orow[tid + 256] = zz;
    const int lane = tid & 63;
    const int t = blockIdx.x * 4 + (tid >> 6);
    float xv[8];
#pragma unroll
    for (int i = 0; i < 8; ++i) xv[i] = x[(size_t)t * DDIM + lane + 64 * i];
    // bf16 copy of x (coalesced) for ffn1's gathered staging
#pragma unroll
    for (int i = 0; i < 8; ++i) xb[(size_t)t * DDIM + lane + 64 * i] = f2b(xv[i]);
    float lg[8];
#pragma unroll
    for (int e = 0; e < 8; ++e) {
      float a = 0.f;
#pragma unroll
      for (int i = 0; i < 8; ++i) a += xv[i] * gw[e * DDIM + lane + 64 * i];
#pragma unroll
      for (int s = 32; s; s >>= 1) a += __shfl_xor(a, s, 64);
      lg[e] = a;
    }
    if (lane < 8) logits[(size_t)t * 8 + lane] = lg[lane];
    if (lane == 0) {
      int i0 = 0; float v0 = lg[0];
#pragma unroll
      for (int e = 1; e < 8; ++e) { if (lg[e] > v0) { v0 = lg[e]; i0 = e; } }
      int i1 = -1; float v1 = -3.4e38f;
#pragma unroll
      for (int e = 0; e < 8; ++e) { if (e != i0 && lg[e] > v1) { v1 = lg[e]; i1 = e; } }
      float ex = expf(v1 - v0);
      float inv = 1.f / (1.f + ex);
      tok_e[t] = i0 | (i1 << 4);
      tok_w[t] = make_float2(inv, ex * inv);
    }
    return;
  }
  // w1 / w3 conversion into fragment-tiled layout (C = 512, KT = 16)
  int bid = blockIdx.x - TTOK / 4;             // 0..4095
  const float* src = (bid < 2048) ? w1 : w3;
  ushort* dst = (bid < 2048) ? w1t : w3t;
  if (bid >= 2048) bid -= 2048;
  const int r0 = (bid >> 2) * 32;
  const int c0 = (bid & 3) * 128;
#pragma unroll
  for (int i = 0; i < 4; ++i) {
    int j = i * 1024 + tid * 4;
    int lr = j >> 7, lc = j & 127;
    float4 v = *(const float4*)&src[(size_t)(r0 + lr) * 512 + c0 + lc];
    ushort4 b = { f2b(v.x), f2b(v.y), f2b(v.z), f2b(v.w) };
    int ord = (lr >> 4) * 4 + (lc >> 5);
    int slot = (lr & 15) + 16 * ((lc >> 3) & 3);
    *(ushort4*)&sm[(ord * 64 + slot) * 8 + (lc & 7)] = b;
  }
  __syncthreads();
  const size_t tb0 = ((size_t)(r0 >> 4) * 16 + (c0 >> 5)) * 512;
#pragma unroll
  for (int rt = 0; rt < 2; ++rt)
    *(short8*)&dst[tb0 + (size_t)rt * 16 * 512 + tid * 8] =
        *(const short8*)&sm[rt * 2048 + tid * 8];
}

// ---------------- router pass 2: per-expert compaction, ballot prefix
__global__ __launch_bounds__(1024) void k_build(
    const int* __restrict__ tok_e, const float2* __restrict__ tok_w,
    int* __restrict__ counts, int* __restrict__ lists, float* __restrict__ wts)
{
  const int e = blockIdx.x;
  const int tid = threadIdx.x;
  const int lane = tid & 63, wid = tid >> 6;
  __shared__ int wcnt[16];
  __shared__ int sbase;
  if (tid == 0) sbase = 0;
  __syncthreads();

  for (int c = 0; c < TTOK; c += 1024) {
    int t = c + tid;
    int pe = tok_e[t];
    bool m0 = (pe & 15) == e;
    bool m1 = ((pe >> 4) & 15) == e;
    bool m = m0 || m1;
    unsigned long long b = __ballot(m);
    int lpre = __popcll(b & ((1ull << lane) - 1ull));
    if (lane == 0) wcnt[wid] = __popcll(b);
    __syncthreads();
    int woff = 0;
#pragma unroll
    for (int i = 0; i < 16; ++i) if (i < wid) woff += wcnt[i];
    if (m) {
      float2 w = tok_w[t];
      int pos = sbase + woff + lpre;
      lists[e * TTOK + pos] = t;
      wts[e * TTOK + pos] = m0 ? w.x : w.y;
    }
    __syncthreads();
    if (tid == 0) {
      int s = 0;
#pragma unroll
      for (int i = 0; i < 16; ++i) s += wcnt[i];
      sbase += s;
    }
    __syncthreads();
  }
  if (tid == 0) counts[e] = sbase;
}

// ---------------- fat GEMM1: H = silu(X W1^T) * (X W3^T)
//                  + w2 cvt, INTERLEAVED (1 cvt 8-round per 2 gemm 8-rounds)
// 8 waves (2x4), 128x128 tile, BK=32. Asymmetric prefetch, queue-verified:
// X (gathered) 4-ring issued 3-ahead; W1/W3 (contiguous) 3-ring issued
// 2-ahead; W issued BEFORE X each iter. Steady vmcnt(7) leaves
// {X(t+1..t+3), W(t+1..t+2)} = 7 loads. Fragment-tiled LDS (conflict-free),
// LDS-staged coalesced H epilogue.
__global__ __launch_bounds__(512) void k_ffn1(
    const ushort* __restrict__ xb, const ushort* __restrict__ w1t,
    const ushort* __restrict__ w3t, const int* __restrict__ counts,
    const int* __restrict__ lists, ushort* __restrict__ H,
    const float* __restrict__ w2, ushort* __restrict__ w2t)
{
  // X: 4 x 8KB (bytes 0..32767) | W: 3 x (W1 8KB + W3 8KB) (bytes 32768..81919)
  __shared__ ushort smem[40960];
  const int tid = threadIdx.x;

  // role by 8-block round: rounds 0,1 of each 3 -> GEMM; round 2 -> w2 cvt.
  const int grp = blockIdx.x >> 3, lane8 = blockIdx.x & 7;
  const int q3 = grp % 3, gq = grp / 3;

  if (q3 == 2) {
    // ---- w2 conversion path (C = 2048, KT = 64), 512 threads
    int bid = gq * 8 + lane8;                  // 0..2047
    ushort* sm = smem;
    const int r0 = (bid >> 4) * 32;
    const int c0 = (bid & 15) * 128;
#pragma unroll
    for (int i = 0; i < 2; ++i) {
      int j = i * 2048 + tid * 4;
      int lr = j >> 7, lc = j & 127;
      float4 v = *(const float4*)&w2[(size_t)(r0 + lr) * 2048 + c0 + lc];
      ushort4 b = { f2b(v.x), f2b(v.y), f2b(v.z), f2b(v.w) };
      int ord = (lr >> 4) * 4 + (lc >> 5);
      int slot = (lr & 15) + 16 * ((lc >> 3) & 3);
      *(ushort4*)&sm[(ord * 64 + slot) * 8 + (lc & 7)] = b;
    }
    __syncthreads();
    const size_t tb0 = ((size_t)(r0 >> 4) * 64 + (c0 >> 5)) * 512;
    int rt = tid >> 8, s = tid & 255;
    *(short8*)&w2t[tb0 + (size_t)rt * 64 * 512 + s * 8] =
        *(const short8*)&sm[rt * 2048 + s * 8];
    return;
  }

  const int gemmid = (gq * 2 + q3) * 8 + lane8;   // 0..4095, gemmid%8 == bid%8
  const int widx = (gemmid & 7) * 512 + (gemmid >> 3);
  const int mt = widx & 31, e = (widx >> 5) & 7, ft = widx >> 8;
  const int ne = counts[e];
  const int m0 = mt * 128;
  if (m0 >= ne) return;
  const int f0 = ft * 128;
  int hb = 0;
#pragma unroll
  for (int i = 0; i < 7; ++i) if (i < e) hb += (counts[i] + 31) & ~31;
  const int wid = tid >> 6, lane = tid & 63;
  const int wm = wid >> 2, wn = wid & 3;       // 2 x 4 wave grid
  const int lr = lane & 15, lgp = lane >> 4;

  const int rtX0 = (hb + m0) >> 4;
  // per-lane token (no LDS toks array): lane l stages row m0+wid*16+(l&15)
  int myp = m0 + wid * 16 + lr;
  const int mytok = lists[e * TTOK + ((myp < ne) ? myp : m0)];
  const ushort* sx = xb + (size_t)mytok * DDIM + lgp * 8;
  const ushort* s1 = w1t + ((size_t)(e * 128 + (f0 >> 4) + wid) * 16) * 512 + lane * 8;
  const ushort* s3 = w3t + ((size_t)(e * 128 + (f0 >> 4) + wid) * 16) * 512 + lane * 8;

#define FFN1_STAGE_X(B)                                                     \
  { load16((char*)smem + (B) * 8192 + wid * 1024, sx); sx += 32; }

#define FFN1_STAGE_W(B)                                                     \
  { char* bw = (char*)smem + 32768 + (B) * 16384 + wid * 1024;              \
    load16(bw, s1);                                                         \
    load16(bw + 8192, s3);                                                  \
    s1 += 512; s3 += 512; }

#define FFN1_COMPUTE(BX, BW)                                                \
  { const ushort* cx = smem + (BX) * 4096;                                  \
    const ushort* cw = smem + 16384 + (BW) * 8192;                          \
    short8 af[4], b1[2], b3[2];                                             \
    _Pragma("unroll")                                                       \
    for (int mf = 0; mf < 4; ++mf)                                          \
      af[mf] = *(const short8*)&cx[(wm * 4 + mf) * 512 + lane * 8];         \
    _Pragma("unroll")                                                       \
    for (int nf = 0; nf < 2; ++nf) {                                        \
      b1[nf] = *(const short8*)&cw[(wn * 2 + nf) * 512 + lane * 8];         \
      b3[nf] = *(const short8*)&cw[4096 + (wn * 2 + nf) * 512 + lane * 8];  \
    }                                                                       \
    _Pragma("unroll")                                                       \
    for (int mf = 0; mf < 4; ++mf)                                          \
      _Pragma("unroll")                                                     \
      for (int nf = 0; nf < 2; ++nf) {                                      \
        acc1[mf][nf] = __builtin_amdgcn_mfma_f32_16x16x32_bf16(             \
            af[mf], b1[nf], acc1[mf][nf], 0, 0, 0);                         \
        acc3[mf][nf] = __builtin_amdgcn_mfma_f32_16x16x32_bf16(             \
            af[mf], b3[nf], acc3[mf][nf], 0, 0, 0);                         \
      } }

  floatx4 acc1[4][2], acc3[4][2];
#pragma unroll
  for (int a = 0; a < 4; ++a)
#pragma unroll
    for (int b = 0; b < 2; ++b) { acc1[a][b] = (floatx4)0.f; acc3[a][b] = (floatx4)0.f; }

  // Queue-verified asymmetric pipeline (per-wave issue order shown):
  // prologue: W0(2), X0, W1(2), X1, X2  -> 7 outstanding
  // iter t:   issue W(t+2)(2) then X(t+3); wait vmcnt(7) leaves
  //           {W(t+1),W(t+2),X(t+1),X(t+2),X(t+3)} -> X has 3-phase flight,
  //           W 2-phase. Tail: t=13 -> 6, t=14 -> 3, t=15 -> 0.
  FFN1_STAGE_W(0);
  FFN1_STAGE_X(0);
  FFN1_STAGE_W(1);
  FFN1_STAGE_X(1);
  FFN1_STAGE_X(2);
#pragma unroll
  for (int t = 0; t < 16; ++t) {                       // K = 512/32
    if (t + 2 < 16) FFN1_STAGE_W((t + 2) % 3);
    if (t + 3 < 16) FFN1_STAGE_X((t + 3) & 3);
    if (t < 13)      asm volatile("s_waitcnt vmcnt(7)" ::: "memory");
    else if (t < 14) asm volatile("s_waitcnt vmcnt(6)" ::: "memory");
    else if (t < 15) asm volatile("s_waitcnt vmcnt(3)" ::: "memory");
    else             asm volatile("s_waitcnt vmcnt(0)" ::: "memory");
    BAR(); SBAR();
    FFN1_COMPUTE(t & 3, t % 3);
    SBAR(); BAR();
  }

  // epilogue: silu*mul -> stage H tile (128x128) in LDS fragment-tile layout,
  // then coalesced short8 stores (row-guarded).
  __syncthreads();                    // all waves done with staging buffers
  ushort* hstage = smem;              // reuse 32KB (X region) of staging LDS
#pragma unroll
  for (int mf = 0; mf < 4; ++mf) {
#pragma unroll
    for (int nf = 0; nf < 2; ++nf) {
      const int tloc = (wm * 4 + mf) * 4 + wn;        // local tile 0..31
      const int slotc = (nf * 2 + (lr >> 3)) & 3;
      const int bidx = tloc * 512 + slotc * 128 + (lr & 7);
      floatx4 v1 = acc1[mf][nf], v3 = acc3[mf][nf];
#pragma unroll
      for (int j = 0; j < 4; ++j) {
        float h1 = v1[j], h3 = v3[j];
        float sig = 1.f / (1.f + __expf(-h1));
        hstage[bidx + (lgp * 4 + j) * 8] = f2b(h1 * sig * h3);
      }
    }
  }
  __syncthreads();
  const int ktBase = f0 >> 5;
#pragma unroll
  for (int i = 0; i < 4; ++i) {
    int s = i * 512 + tid;            // short8 index 0..2047
    int tloc = s >> 6, off = s & 63;  // tile, slot
    int rt_l = tloc >> 2, kt_l = tloc & 3;
    if (m0 + rt_l * 16 + (off & 15) < ne)
      *(short8*)&H[((size_t)(rtX0 + rt_l) * 64 + ktBase + kt_l) * 512 + off * 8] =
          *(const short8*)&hstage[s * 8];
  }
#undef FFN1_STAGE_X
#undef FFN1_STAGE_W
#undef FFN1_COMPUTE
}

// ---------------- GEMM2: Y = H W2^T, BK=64, K-split 2, R9 counted-vmcnt
__global__ __launch_bounds__(512) void k_ffn2(
    const ushort* __restrict__ Ht, const ushort* __restrict__ w2t,
    const int* __restrict__ counts, const int* __restrict__ lists,
    const float* __restrict__ wts, float* __restrict__ out)
{
  const int bid = blockIdx.x;                  // nwg = 2048
  const int widx = (bid & 7) * 256 + (bid >> 3);
  const int mt = widx & 31, e = (widx >> 5) & 7;
  const int rest = widx >> 8;                  // 0..7
  const int dt = rest & 3, ks = rest >> 2;
  const int ne = counts[e];
  const int m0 = mt * 128;
  if (m0 >= ne) return;
  const int d0 = dt * 128;
  int hb = 0;
#pragma unroll
  for (int i = 0; i < 7; ++i) if (i < e) hb += (counts[i] + 31) & ~31;
  const int tid = threadIdx.x;
  const int wid = tid >> 6, lane = tid & 63;
  const int wm = wid >> 2, wn = wid & 3;
  const int lr = lane & 15, lgp = lane >> 4;

  __shared__ ushort Hls[2][8192], W2ls[2][8192];
  __shared__ int toks[128];
  __shared__ float twt[128];

  if (tid < 128) {
    int p = m0 + tid;
    bool v = p < ne;
    toks[tid] = v ? lists[e * TTOK + p] : 0;
    twt[tid] = v ? wts[e * TTOK + p] : 0.f;
  }

  const int rtH0 = (hb + m0) >> 4;
  const int kb = ks * 32;                      // K-tile base (32-col units)
  const ushort* sh = Ht  + ((size_t)(rtH0 + wid) * 64 + kb) * 512 + lane * 8;
  const ushort* sw = w2t + ((size_t)(e * 32 + (d0 >> 4) + wid) * 64 + kb) * 512 + lane * 8;

#define FFN2_STAGE(B)                                                      \
  { load16((char*)&Hls[B][0]  + (wid * 2) * 1024, sh);                     \
    load16((char*)&Hls[B][0]  + (wid * 2 + 1) * 1024, sh + 512);           \
    load16((char*)&W2ls[B][0] + (wid * 2) * 1024, sw);                     \
    load16((char*)&W2ls[B][0] + (wid * 2 + 1) * 1024, sw + 512);           \
    sh += 1024; sw += 1024; }

#define FFN2_COMPUTE(B)                                                    \
  { _Pragma("unroll")                                                      \
    for (int kk = 0; kk < 2; ++kk) {                                       \
      short8 af[4], bf[2];                                                 \
      _Pragma("unroll")                                                    \
      for (int mf = 0; mf < 4; ++mf)                                       \
        af[mf] = *(const short8*)&Hls[B][((wm * 4 + mf) * 2 + kk) * 512 + lane * 8]; \
      _Pragma("unroll")                                                    \
      for (int nf = 0; nf < 2; ++nf)                                       \
        bf[nf] = *(const short8*)&W2ls[B][((wn * 2 + nf) * 2 + kk) * 512 + lane * 8]; \
      _Pragma("unroll")                                                    \
      for (int mf = 0; mf < 4; ++mf)                                       \
        _Pragma("unroll")                                                  \
        for (int nf = 0; nf < 2; ++nf)                                     \
          acc[mf][nf] = __builtin_amdgcn_mfma_f32_16x16x32_bf16(           \
              af[mf], bf[nf], acc[mf][nf], 0, 0, 0);                       \
    } }

  floatx4 acc[4][2];
#pragma unroll
  for (int a = 0; a < 4; ++a)
#pragma unroll
    for (int b = 0; b < 2; ++b) acc[a][b] = (floatx4)0.f;

  FFN2_STAGE(0);
  for (int t = 0; t < 16; t += 2) {            // K = 1024/64 per split
    FFN2_STAGE(1);
    asm volatile("s_waitcnt vmcnt(4)" ::: "memory");
    BAR(); SBAR();
    FFN2_COMPUTE(0);
    SBAR(); BAR();
    if (t + 2 < 16) {
      FFN2_STAGE(0);
      asm volatile("s_waitcnt vmcnt(4)" ::: "memory");
    } else {
      asm volatile("s_waitcnt vmcnt(0)" ::: "memory");
    }
    BAR(); SBAR();
    FFN2_COMPUTE(1);
    SBAR(); BAR();
  }

#pragma unroll
  for (int mf = 0; mf < 4; ++mf) {
#pragma unroll
    for (int j = 0; j < 4; ++j) {
      int rloc = wm * 64 + mf * 16 + lgp * 4 + j;
      int p = m0 + rloc;
      if (p < ne) {
        int t = toks[rloc];
        float w = twt[rloc];
#pragma unroll
        for (int nf = 0; nf < 2; ++nf) {
          int d = d0 + wn * 32 + nf * 16 + lr;
          atomicAdd(&out[(size_t)t * DDIM + d], w * acc[mf][nf][j]);
        }
      }
    }
  }
#undef FFN2_STAGE
#undef FFN2_COMPUTE
}

extern "C" void kernel_launch(void* const* d_in, const int* in_sizes, int n_in,
                              void* d_out, int out_size, void* d_ws, size_t ws_size,
                              hipStream_t stream) {
  const float* x  = (const float*)d_in[0];
  const float* gw = (const float*)d_in[1];
  const float* w1 = (const float*)d_in[2];
  const float* w2 = (const float*)d_in[3];
  const float* w3 = (const float*)d_in[4];
  float* out = (float*)d_out;
  float* logits = out + (size_t)TTOK * DDIM;

  // workspace layout (~90 MB)
  int* counts = (int*)d_ws;                        // [8] (pad to 16)
  int* tok_e  = counts + 16;                       // [4096]
  float2* tok_w = (float2*)(tok_e + TTOK);         // [4096]
  int* lists  = (int*)(tok_w + TTOK);              // [8][4096]
  float* wts  = (float*)(lists + NEXP * TTOK);     // [8][4096]
  ushort* xb  = (ushort*)(wts + NEXP * TTOK);      // [4096][512] bf16 rows
  ushort* w1t = xb + (size_t)TTOK * DDIM;          // tiled
  ushort* w3t = w1t + (size_t)NEXP * FDIM * DDIM;
  ushort* w2t = w3t + (size_t)NEXP * FDIM * DDIM;  // tiled
  ushort* H   = w2t + (size_t)NEXP * DDIM * FDIM;  // tiled [HROWS][2048]

  k_front<<<TTOK / 4 + 4096, 256, 0, stream>>>(x, gw, logits, tok_e, tok_w,
                                               out, xb, w1, w1t, w3, w3t);
  k_build<<<NEXP, 1024, 0, stream>>>(tok_e, tok_w, counts, lists, wts);

  k_ffn1<<<4096 + 2048, 512, 0, stream>>>(xb, w1t, w3t, counts, lists, H, w2, w2t);
  k_ffn2<<<2048, 512, 0, stream>>>(H, w2t, counts, lists, wts, out);
}

// Round 21
// 133.194 us; speedup vs baseline: 1.0402x; 1.0062x over previous
//
#include <hip/hip_runtime.h>

#define TTOK 4096
#define NEXP 8
#define DDIM 512
#define FDIM 2048
#define HROWS 8576   // padded-compact row allocation (max used 8440 + slack)

typedef __attribute__((ext_vector_type(8))) short short8;
typedef __attribute__((ext_vector_type(4))) float floatx4;

#define BAR()  __builtin_amdgcn_s_barrier()
#define SBAR() __builtin_amdgcn_sched_barrier(0)

__device__ __forceinline__ ushort f2b(float f) {
  unsigned u = __float_as_uint(f);
  u += 0x7fffu + ((u >> 16) & 1u);   // round-to-nearest-even bf16
  return (ushort)(u >> 16);
}

__device__ __forceinline__ void load16(void* lds, const void* g) {
  __builtin_amdgcn_global_load_lds(
      (const __attribute__((address_space(1))) unsigned int*)g,
      (__attribute__((address_space(3))) unsigned int*)lds, 16, 0, 0);
}

// Fragment-tile layout (16x16x32 MFMA operands): matrix [R][C] stored as
// 16-row x 32-col tiles of 1KB. Tile (rt,kt) at ((rt*(C/32))+kt)*512 elems.
// elem (r,c): slot = (r&15) + 16*((c>>3)&3), ushort idx = slot*8+(c&7).
// Wave fragment read = lane l reads tile+l*16B -> conflict-free ds_read_b128.

// ---------------- fat front: logits+top2+zero-out+xb (blocks 0..1023) | w1/w3 cvt
__global__ __launch_bounds__(256) void k_front(
    const float* __restrict__ x, const float* __restrict__ gw,
    float* __restrict__ logits, int* __restrict__ tok_e,
    float2* __restrict__ tok_w, float* __restrict__ outz,
    ushort* __restrict__ xb,
    const float* __restrict__ w1, ushort* __restrict__ w1t,
    const float* __restrict__ w3, ushort* __restrict__ w3t)
{
  __shared__ ushort sm[4096];
  const int tid = threadIdx.x;
  if (blockIdx.x < TTOK / 4) {
    // zero the out rows for these 4 tokens (replaces hipMemsetAsync)
    float4 zz = {0.f, 0.f, 0.f, 0.f};
    float4* orow = (float4*)(outz + (size_t)blockIdx.x * 4 * DDIM);
    orow[tid] = zz;
    orow[tid + 256] = zz;
    const int lane = tid & 63;
    const int t = blockIdx.x * 4 + (tid >> 6);
    float xv[8];
#pragma unroll
    for (int i = 0; i < 8; ++i) xv[i] = x[(size_t)t * DDIM + lane + 64 * i];
    // bf16 copy of x (coalesced) for ffn1's gathered staging
#pragma unroll
    for (int i = 0; i < 8; ++i) xb[(size_t)t * DDIM + lane + 64 * i] = f2b(xv[i]);
    float lg[8];
#pragma unroll
    for (int e = 0; e < 8; ++e) {
      float a = 0.f;
#pragma unroll
      for (int i = 0; i < 8; ++i) a += xv[i] * gw[e * DDIM + lane + 64 * i];
#pragma unroll
      for (int s = 32; s; s >>= 1) a += __shfl_xor(a, s, 64);
      lg[e] = a;
    }
    if (lane < 8) logits[(size_t)t * 8 + lane] = lg[lane];
    if (lane == 0) {
      int i0 = 0; float v0 = lg[0];
#pragma unroll
      for (int e = 1; e < 8; ++e) { if (lg[e] > v0) { v0 = lg[e]; i0 = e; } }
      int i1 = -1; float v1 = -3.4e38f;
#pragma unroll
      for (int e = 0; e < 8; ++e) { if (e != i0 && lg[e] > v1) { v1 = lg[e]; i1 = e; } }
      float ex = expf(v1 - v0);
      float inv = 1.f / (1.f + ex);
      tok_e[t] = i0 | (i1 << 4);
      tok_w[t] = make_float2(inv, ex * inv);
    }
    return;
  }
  // w1 / w3 conversion into fragment-tiled layout (C = 512, KT = 16)
  int bid = blockIdx.x - TTOK / 4;             // 0..4095
  const float* src = (bid < 2048) ? w1 : w3;
  ushort* dst = (bid < 2048) ? w1t : w3t;
  if (bid >= 2048) bid -= 2048;
  const int r0 = (bid >> 2) * 32;
  const int c0 = (bid & 3) * 128;
#pragma unroll
  for (int i = 0; i < 4; ++i) {
    int j = i * 1024 + tid * 4;
    int lr = j >> 7, lc = j & 127;
    float4 v = *(const float4*)&src[(size_t)(r0 + lr) * 512 + c0 + lc];
    ushort4 b = { f2b(v.x), f2b(v.y), f2b(v.z), f2b(v.w) };
    int ord = (lr >> 4) * 4 + (lc >> 5);
    int slot = (lr & 15) + 16 * ((lc >> 3) & 3);
    *(ushort4*)&sm[(ord * 64 + slot) * 8 + (lc & 7)] = b;
  }
  __syncthreads();
  const size_t tb0 = ((size_t)(r0 >> 4) * 16 + (c0 >> 5)) * 512;
#pragma unroll
  for (int rt = 0; rt < 2; ++rt)
    *(short8*)&dst[tb0 + (size_t)rt * 16 * 512 + tid * 8] =
        *(const short8*)&sm[rt * 2048 + tid * 8];
}

// ---------------- router pass 2: per-expert compaction, ballot prefix
__global__ __launch_bounds__(1024) void k_build(
    const int* __restrict__ tok_e, const float2* __restrict__ tok_w,
    int* __restrict__ counts, int* __restrict__ lists, float* __restrict__ wts)
{
  const int e = blockIdx.x;
  const int tid = threadIdx.x;
  const int lane = tid & 63, wid = tid >> 6;
  __shared__ int wcnt[16];
  __shared__ int sbase;
  if (tid == 0) sbase = 0;
  __syncthreads();

  for (int c = 0; c < TTOK; c += 1024) {
    int t = c + tid;
    int pe = tok_e[t];
    bool m0 = (pe & 15) == e;
    bool m1 = ((pe >> 4) & 15) == e;
    bool m = m0 || m1;
    unsigned long long b = __ballot(m);
    int lpre = __popcll(b & ((1ull << lane) - 1ull));
    if (lane == 0) wcnt[wid] = __popcll(b);
    __syncthreads();
    int woff = 0;
#pragma unroll
    for (int i = 0; i < 16; ++i) if (i < wid) woff += wcnt[i];
    if (m) {
      float2 w = tok_w[t];
      int pos = sbase + woff + lpre;
      lists[e * TTOK + pos] = t;
      wts[e * TTOK + pos] = m0 ? w.x : w.y;
    }
    __syncthreads();
    if (tid == 0) {
      int s = 0;
#pragma unroll
      for (int i = 0; i < 16; ++i) s += wcnt[i];
      sbase += s;
    }
    __syncthreads();
  }
  if (tid == 0) counts[e] = sbase;
}

// ---------------- fat GEMM1: H = silu(X W1^T) * (X W3^T)
//                  + w2 cvt, INTERLEAVED (1 cvt 8-round per 2 gemm 8-rounds)
// 8 waves (2x4), 128x128 tile, BK=32. 48KB LDS (X 2-ring + W 2-ring) ->
// 3 blocks/CU for TLP-based latency hiding; depth-1 counted-vmcnt (W-first,
// queue-verified). Fragment-tiled LDS (conflict-free), LDS-staged coalesced
// H epilogue.
__global__ __launch_bounds__(512) void k_ffn1(
    const ushort* __restrict__ xb, const ushort* __restrict__ w1t,
    const ushort* __restrict__ w3t, const int* __restrict__ counts,
    const int* __restrict__ lists, ushort* __restrict__ H,
    const float* __restrict__ w2, ushort* __restrict__ w2t)
{
  // X: 2 x 8KB (bytes 0..16383) | W: 2 x (W1 8KB + W3 8KB) (bytes 16384..49151)
  __shared__ ushort smem[24576];
  const int tid = threadIdx.x;

  // role by 8-block round: rounds 0,1 of each 3 -> GEMM; round 2 -> w2 cvt.
  const int grp = blockIdx.x >> 3, lane8 = blockIdx.x & 7;
  const int q3 = grp % 3, gq = grp / 3;

  if (q3 == 2) {
    // ---- w2 conversion path (C = 2048, KT = 64), 512 threads
    int bid = gq * 8 + lane8;                  // 0..2047
    ushort* sm = smem;
    const int r0 = (bid >> 4) * 32;
    const int c0 = (bid & 15) * 128;
#pragma unroll
    for (int i = 0; i < 2; ++i) {
      int j = i * 2048 + tid * 4;
      int lr = j >> 7, lc = j & 127;
      float4 v = *(const float4*)&w2[(size_t)(r0 + lr) * 2048 + c0 + lc];
      ushort4 b = { f2b(v.x), f2b(v.y), f2b(v.z), f2b(v.w) };
      int ord = (lr >> 4) * 4 + (lc >> 5);
      int slot = (lr & 15) + 16 * ((lc >> 3) & 3);
      *(ushort4*)&sm[(ord * 64 + slot) * 8 + (lc & 7)] = b;
    }
    __syncthreads();
    const size_t tb0 = ((size_t)(r0 >> 4) * 64 + (c0 >> 5)) * 512;
    int rt = tid >> 8, s = tid & 255;
    *(short8*)&w2t[tb0 + (size_t)rt * 64 * 512 + s * 8] =
        *(const short8*)&sm[rt * 2048 + s * 8];
    return;
  }

  const int gemmid = (gq * 2 + q3) * 8 + lane8;   // 0..4095, gemmid%8 == bid%8
  const int widx = (gemmid & 7) * 512 + (gemmid >> 3);
  const int mt = widx & 31, e = (widx >> 5) & 7, ft = widx >> 8;
  const int ne = counts[e];
  const int m0 = mt * 128;
  if (m0 >= ne) return;
  const int f0 = ft * 128;
  int hb = 0;
#pragma unroll
  for (int i = 0; i < 7; ++i) if (i < e) hb += (counts[i] + 31) & ~31;
  const int wid = tid >> 6, lane = tid & 63;
  const int wm = wid >> 2, wn = wid & 3;       // 2 x 4 wave grid
  const int lr = lane & 15, lgp = lane >> 4;

  const int rtX0 = (hb + m0) >> 4;
  // per-lane token: lane l stages row m0+wid*16+(l&15), colgroup (l>>4)
  int myp = m0 + wid * 16 + lr;
  const int mytok = lists[e * TTOK + ((myp < ne) ? myp : m0)];
  const ushort* sx = xb + (size_t)mytok * DDIM + lgp * 8;
  const ushort* s1 = w1t + ((size_t)(e * 128 + (f0 >> 4) + wid) * 16) * 512 + lane * 8;
  const ushort* s3 = w3t + ((size_t)(e * 128 + (f0 >> 4) + wid) * 16) * 512 + lane * 8;

#define FFN1_STAGE_X(B)                                                     \
  { load16((char*)smem + (B) * 8192 + wid * 1024, sx); sx += 32; }

#define FFN1_STAGE_W(B)                                                     \
  { char* bw = (char*)smem + 16384 + (B) * 16384 + wid * 1024;              \
    load16(bw, s1);                                                         \
    load16(bw + 8192, s3);                                                  \
    s1 += 512; s3 += 512; }

#define FFN1_COMPUTE(BX, BW)                                                \
  { const ushort* cx = smem + (BX) * 4096;                                  \
    const ushort* cw = smem + 8192 + (BW) * 8192;                           \
    short8 af[4], b1[2], b3[2];                                             \
    _Pragma("unroll")                                                       \
    for (int mf = 0; mf < 4; ++mf)                                          \
      af[mf] = *(const short8*)&cx[(wm * 4 + mf) * 512 + lane * 8];         \
    _Pragma("unroll")                                                       \
    for (int nf = 0; nf < 2; ++nf) {                                        \
      b1[nf] = *(const short8*)&cw[(wn * 2 + nf) * 512 + lane * 8];         \
      b3[nf] = *(const short8*)&cw[4096 + (wn * 2 + nf) * 512 + lane * 8];  \
    }                                                                       \
    _Pragma("unroll")                                                       \
    for (int mf = 0; mf < 4; ++mf)                                          \
      _Pragma("unroll")                                                     \
      for (int nf = 0; nf < 2; ++nf) {                                      \
        acc1[mf][nf] = __builtin_amdgcn_mfma_f32_16x16x32_bf16(             \
            af[mf], b1[nf], acc1[mf][nf], 0, 0, 0);                         \
        acc3[mf][nf] = __builtin_amdgcn_mfma_f32_16x16x32_bf16(             \
            af[mf], b3[nf], acc3[mf][nf], 0, 0, 0);                         \
      } }

  floatx4 acc1[4][2], acc3[4][2];
#pragma unroll
  for (int a = 0; a < 4; ++a)
#pragma unroll
    for (int b = 0; b < 2; ++b) { acc1[a][b] = (floatx4)0.f; acc3[a][b] = (floatx4)0.f; }

  // Depth-1 counted-vmcnt, queue-verified (1 X + 2 W loads per iter, W first):
  // prologue {W0(2), X0}; iter t issues W(t+1)(2), X(t+1); wait vmcnt(3)
  // drains {W(t), X(t)}, leaves {W(t+1), X(t+1)}. t=15 -> vmcnt(0).
  // Buffer (t+1)&1 was computed at iter t-1; its trailing barrier passed.
  FFN1_STAGE_W(0);
  FFN1_STAGE_X(0);
#pragma unroll
  for (int t = 0; t < 16; ++t) {                       // K = 512/32
    if (t + 1 < 16) {
      FFN1_STAGE_W((t + 1) & 1);
      FFN1_STAGE_X((t + 1) & 1);
      asm volatile("s_waitcnt vmcnt(3)" ::: "memory");
    } else {
      asm volatile("s_waitcnt vmcnt(0)" ::: "memory");
    }
    BAR(); SBAR();
    FFN1_COMPUTE(t & 1, t & 1);
    SBAR(); BAR();
  }

  // epilogue: silu*mul -> stage H tile (128x128) in LDS fragment-tile layout,
  // then coalesced short8 stores (row-guarded).
  __syncthreads();                    // all waves done with staging buffers
  ushort* hstage = smem;              // reuse 32KB of the 48KB staging LDS
#pragma unroll
  for (int mf = 0; mf < 4; ++mf) {
#pragma unroll
    for (int nf = 0; nf < 2; ++nf) {
      const int tloc = (wm * 4 + mf) * 4 + wn;        // local tile 0..31
      const int slotc = (nf * 2 + (lr >> 3)) & 3;
      const int bidx = tloc * 512 + slotc * 128 + (lr & 7);
      floatx4 v1 = acc1[mf][nf], v3 = acc3[mf][nf];
#pragma unroll
      for (int j = 0; j < 4; ++j) {
        float h1 = v1[j], h3 = v3[j];
        float sig = 1.f / (1.f + __expf(-h1));
        hstage[bidx + (lgp * 4 + j) * 8] = f2b(h1 * sig * h3);
      }
    }
  }
  __syncthreads();
  const int ktBase = f0 >> 5;
#pragma unroll
  for (int i = 0; i < 4; ++i) {
    int s = i * 512 + tid;            // short8 index 0..2047
    int tloc = s >> 6, off = s & 63;  // tile, slot
    int rt_l = tloc >> 2, kt_l = tloc & 3;
    if (m0 + rt_l * 16 + (off & 15) < ne)
      *(short8*)&H[((size_t)(rtX0 + rt_l) * 64 + ktBase + kt_l) * 512 + off * 8] =
          *(const short8*)&hstage[s * 8];
  }
#undef FFN1_STAGE_X
#undef FFN1_STAGE_W
#undef FFN1_COMPUTE
}

// ---------------- GEMM2: Y = H W2^T, BK=64, K-split 2, R9 counted-vmcnt
__global__ __launch_bounds__(512) void k_ffn2(
    const ushort* __restrict__ Ht, const ushort* __restrict__ w2t,
    const int* __restrict__ counts, const int* __restrict__ lists,
    const float* __restrict__ wts, float* __restrict__ out)
{
  const int bid = blockIdx.x;                  // nwg = 2048
  const int widx = (bid & 7) * 256 + (bid >> 3);
  const int mt = widx & 31, e = (widx >> 5) & 7;
  const int rest = widx >> 8;                  // 0..7
  const int dt = rest & 3, ks = rest >> 2;
  const int ne = counts[e];
  const int m0 = mt * 128;
  if (m0 >= ne) return;
  const int d0 = dt * 128;
  int hb = 0;
#pragma unroll
  for (int i = 0; i < 7; ++i) if (i < e) hb += (counts[i] + 31) & ~31;
  const int tid = threadIdx.x;
  const int wid = tid >> 6, lane = tid & 63;
  const int wm = wid >> 2, wn = wid & 3;
  const int lr = lane & 15, lgp = lane >> 4;

  __shared__ ushort Hls[2][8192], W2ls[2][8192];
  __shared__ int toks[128];
  __shared__ float twt[128];

  if (tid < 128) {
    int p = m0 + tid;
    bool v = p < ne;
    toks[tid] = v ? lists[e * TTOK + p] : 0;
    twt[tid] = v ? wts[e * TTOK + p] : 0.f;
  }

  const int rtH0 = (hb + m0) >> 4;
  const int kb = ks * 32;                      // K-tile base (32-col units)
  const ushort* sh = Ht  + ((size_t)(rtH0 + wid) * 64 + kb) * 512 + lane * 8;
  const ushort* sw = w2t + ((size_t)(e * 32 + (d0 >> 4) + wid) * 64 + kb) * 512 + lane * 8;

#define FFN2_STAGE(B)                                                      \
  { load16((char*)&Hls[B][0]  + (wid * 2) * 1024, sh);                     \
    load16((char*)&Hls[B][0]  + (wid * 2 + 1) * 1024, sh + 512);           \
    load16((char*)&W2ls[B][0] + (wid * 2) * 1024, sw);                     \
    load16((char*)&W2ls[B][0] + (wid * 2 + 1) * 1024, sw + 512);           \
    sh += 1024; sw += 1024; }

#define FFN2_COMPUTE(B)                                                    \
  { _Pragma("unroll")                                                      \
    for (int kk = 0; kk < 2; ++kk) {                                       \
      short8 af[4], bf[2];                                                 \
      _Pragma("unroll")                                                    \
      for (int mf = 0; mf < 4; ++mf)                                       \
        af[mf] = *(const short8*)&Hls[B][((wm * 4 + mf) * 2 + kk) * 512 + lane * 8]; \
      _Pragma("unroll")                                                    \
      for (int nf = 0; nf < 2; ++nf)                                       \
        bf[nf] = *(const short8*)&W2ls[B][((wn * 2 + nf) * 2 + kk) * 512 + lane * 8]; \
      _Pragma("unroll")                                                    \
      for (int mf = 0; mf < 4; ++mf)                                       \
        _Pragma("unroll")                                                  \
        for (int nf = 0; nf < 2; ++nf)                                     \
          acc[mf][nf] = __builtin_amdgcn_mfma_f32_16x16x32_bf16(           \
              af[mf], bf[nf], acc[mf][nf], 0, 0, 0);                       \
    } }

  floatx4 acc[4][2];
#pragma unroll
  for (int a = 0; a < 4; ++a)
#pragma unroll
    for (int b = 0; b < 2; ++b) acc[a][b] = (floatx4)0.f;

  FFN2_STAGE(0);
  for (int t = 0; t < 16; t += 2) {            // K = 1024/64 per split
    FFN2_STAGE(1);
    asm volatile("s_waitcnt vmcnt(4)" ::: "memory");
    BAR(); SBAR();
    FFN2_COMPUTE(0);
    SBAR(); BAR();
    if (t + 2 < 16) {
      FFN2_STAGE(0);
      asm volatile("s_waitcnt vmcnt(4)" ::: "memory");
    } else {
      asm volatile("s_waitcnt vmcnt(0)" ::: "memory");
    }
    BAR(); SBAR();
    FFN2_COMPUTE(1);
    SBAR(); BAR();
  }

#pragma unroll
  for (int mf = 0; mf < 4; ++mf) {
#pragma unroll
    for (int j = 0; j < 4; ++j) {
      int rloc = wm * 64 + mf * 16 + lgp * 4 + j;
      int p = m0 + rloc;
      if (p < ne) {
        int t = toks[rloc];
        float w = twt[rloc];
#pragma unroll
        for (int nf = 0; nf < 2; ++nf) {
          int d = d0 + wn * 32 + nf * 16 + lr;
          atomicAdd(&out[(size_t)t * DDIM + d], w * acc[mf][nf][j]);
        }
      }
    }
  }
#undef FFN2_STAGE
#undef FFN2_COMPUTE
}

extern "C" void kernel_launch(void* const* d_in, const int* in_sizes, int n_in,
                              void* d_out, int out_size, void* d_ws, size_t ws_size,
                              hipStream_t stream) {
  const float* x  = (const float*)d_in[0];
  const float* gw = (const float*)d_in[1];
  const float* w1 = (const float*)d_in[2];
  const float* w2 = (const float*)d_in[3];
  const float* w3 = (const float*)d_in[4];
  float* out = (float*)d_out;
  float* logits = out + (size_t)TTOK * DDIM;

  // workspace layout (~90 MB)
  int* counts = (int*)d_ws;                        // [8] (pad to 16)
  int* tok_e  = counts + 16;                       // [4096]
  float2* tok_w = (float2*)(tok_e + TTOK);         // [4096]
  int* lists  = (int*)(tok_w + TTOK);              // [8][4096]
  float* wts  = (float*)(lists + NEXP * TTOK);     // [8][4096]
  ushort* xb  = (ushort*)(wts + NEXP * TTOK);      // [4096][512] bf16 rows
  ushort* w1t = xb + (size_t)TTOK * DDIM;          // tiled
  ushort* w3t = w1t + (size_t)NEXP * FDIM * DDIM;
  ushort* w2t = w3t + (size_t)NEXP * FDIM * DDIM;  // tiled
  ushort* H   = w2t + (size_t)NEXP * DDIM * FDIM;  // tiled [HROWS][2048]

  k_front<<<TTOK / 4 + 4096, 256, 0, stream>>>(x, gw, logits, tok_e, tok_w,
                                               out, xb, w1, w1t, w3, w3t);
  k_build<<<NEXP, 1024, 0, stream>>>(tok_e, tok_w, counts, lists, wts);

  k_ffn1<<<4096 + 2048, 512, 0, stream>>>(xb, w1t, w3t, counts, lists, H, w2, w2t);
  k_ffn2<<<2048, 512, 0, stream>>>(H, w2t, counts, lists, wts, out);
}